// Round 13
// baseline (316.491 us; speedup 1.0000x reference)
//
#include <hip/hip_runtime.h>
#include <hip/hip_bf16.h>
#include <stdint.h>

#define T_SEQ 2048
#define CDIM  2048
#define NHEAD 16
#define DHEAD 128
#define BT    4096   // B*T
#define BHT   32     // B*H
#define NQKV  6144

typedef __bf16 bf16x8_t __attribute__((ext_vector_type(8)));
typedef float  f32x4_t  __attribute__((ext_vector_type(4)));
typedef unsigned short u16x8_t __attribute__((ext_vector_type(8)));
typedef unsigned short u16x4_t __attribute__((ext_vector_type(4)));

__device__ __forceinline__ unsigned short f2bf(float f){
  unsigned int u = __float_as_uint(f);
  u += 0x7fffu + ((u >> 16) & 1u);
  return (unsigned short)(u >> 16);
}
__device__ __forceinline__ float bf2f(unsigned short h){
  return __uint_as_float(((unsigned int)h) << 16);
}
__device__ __forceinline__ unsigned ldsaddr(const void* p){
  return (unsigned)(size_t)(const __attribute__((address_space(3))) void*)p;
}
__device__ __forceinline__ u16x4_t tr16(unsigned a){
  u16x4_t r;
  asm volatile("ds_read_b64_tr_b16 %0, %1" : "=v"(r) : "v"(a));
  return r;
}

// ------- fused transpose+cast for all 4 weight matrices (grid.z selects) -------
__global__ __launch_bounds__(256) void transpose_all(const float* __restrict__ Wq,
    const float* __restrict__ Wk, const float* __restrict__ Wv,
    const float* __restrict__ Wo, unsigned short* __restrict__ WqkvT,
    unsigned short* __restrict__ WoT){
  __shared__ float tile[32][33];
  const int z = blockIdx.z;
  const float* W = (z==0)?Wq:(z==1)?Wk:(z==2)?Wv:Wo;
  unsigned short* Wt = (z<3) ? (WqkvT + (size_t)z*4194304) : WoT;
  int n0 = blockIdx.x*32, k0 = blockIdx.y*32;
  int tx = threadIdx.x, ty = threadIdx.y;  // 32 x 8
  #pragma unroll
  for (int i=0;i<32;i+=8)
    tile[ty+i][tx] = W[(size_t)(k0+ty+i)*CDIM + n0 + tx];
  __syncthreads();
  #pragma unroll
  for (int i=0;i<32;i+=8)
    Wt[(size_t)(n0+ty+i)*CDIM + k0 + tx] = f2bf(tile[tx][ty+i]);
}

// ---------------- build WgT[32][2048]: c<16 -> fgw[:,c], c>=16 -> wlam[:,c-16] ----------------
__global__ __launch_bounds__(256) void build_wgt(const float* __restrict__ fgw,
                                                 const float* __restrict__ wlam,
                                                 float* __restrict__ WgT){
  int idx = blockIdx.x*256 + threadIdx.x;   // [0, 65536)
  int c = idx >> 11, k = idx & 2047;
  const float* W = (c < 16) ? fgw : wlam;
  WgT[idx] = W[k*16 + (c & 15)];
}

// ========== shared ring-3 phase machinery (T2+T4+T5) ==========
#define V3_SYNC() do{ __builtin_amdgcn_sched_barrier(0); \
  __builtin_amdgcn_s_barrier(); \
  asm volatile("s_waitcnt lgkmcnt(0)" ::: "memory"); \
  __builtin_amdgcn_sched_barrier(0); }while(0)

#define V3_TAIL() do{ asm volatile("s_waitcnt vmcnt(3)" ::: "memory"); \
  __builtin_amdgcn_sched_barrier(0); \
  __builtin_amdgcn_s_barrier(); }while(0)

#define V3_MFMA() do{ __builtin_amdgcn_s_setprio(1); \
  _Pragma("unroll") for (int mi=0;mi<4;mi++) \
  _Pragma("unroll") for (int ni=0;ni<4;ni++) \
    acc[mi][ni] = __builtin_amdgcn_mfma_f32_16x16x32_bf16(af[mi], bfr[ni], acc[mi][ni],0,0,0); \
  __builtin_amdgcn_s_setprio(0); }while(0)

#define V3_PHASE(BUF, TIDX) do{ \
  readA(BUF); readB(BUF); \
  { int ts_ = (TIDX)+2; if (ts_ > ntm1) ts_ = ntm1; stage(((BUF)+2)%3, ts_); } \
  V3_SYNC(); V3_MFMA(); V3_TAIL(); }while(0)

// ========== 128x256 ring-3 GEMM.  MODE 1: QKV with FUSED RoPE+RMSNorm epilogue
// for Q/K blocks (V blocks scatter directly).  MODE 2: f32 plain (Wo). ==========
template<int MODE>
__global__ __launch_bounds__(512, 2) void gemm_v3(const unsigned short* __restrict__ A,
                                                  const unsigned short* __restrict__ Bt,
                                                  void* __restrict__ Cout,
                                                  const float* __restrict__ cosT,
                                                  const float* __restrict__ sinT,
                                                  int M, int N, int K){
  extern __shared__ unsigned short lds[];
  const int nx = N >> 8;               // n-tiles (256 wide)
  const int Mt = M >> 7;               // m-tiles (128 tall)
  const int bid = blockIdx.x;
  const int c8 = bid & 7, w = bid >> 3;
  const int mh = Mt >> 1;
  const int mt = (c8 & 1)*mh + (w % mh);
  const int ntc = (c8 >> 1)*(nx >> 2) + (w / mh);
  const int m0 = mt << 7, n0 = ntc << 8;
  const int tid = threadIdx.x, lane = tid & 63, wv = tid >> 6;
  const int wm = wv >> 2, wn = wv & 3;
  const int g = lane >> 4, qi = lane & 15;
  const int ntm1 = (K >> 5) - 1;

  f32x4_t acc[4][4] = {};
  bf16x8_t af[4], bfr[4];

  int goffA, goffB[2];
  { int s = tid; int row = s >> 2; int lg = (s & 3) ^ ((row >> 1) & 3);
    goffA = row*K + lg*8; }
  #pragma unroll
  for (int j=0;j<2;j++){
    int s = j*512 + tid;
    int row = s >> 2;
    int lg = (s & 3) ^ ((row >> 1) & 3);
    goffB[j] = row*K + lg*8;
  }

  auto stage = [&](int buf, int kt){
    const unsigned short* srcA = A + (size_t)m0*K + kt*32;
    const unsigned short* srcB = Bt + (size_t)n0*K + kt*32;
    unsigned short* base = lds + buf*12288;
    __builtin_amdgcn_global_load_lds(
        (const __attribute__((address_space(1))) void*)(srcA + goffA),
        (__attribute__((address_space(3))) void*)(base + tid*8), 16, 0, 0);
    #pragma unroll
    for (int j=0;j<2;j++)
      __builtin_amdgcn_global_load_lds(
        (const __attribute__((address_space(1))) void*)(srcB + goffB[j]),
        (__attribute__((address_space(3))) void*)(base + 4096 + (j*512 + tid)*8), 16, 0, 0);
  };
  auto readA = [&](int buf){
    const unsigned short* base = lds + buf*12288;
    #pragma unroll
    for (int mi=0;mi<4;mi++){
      int row = wm*64 + mi*16 + qi;
      int gs = g ^ ((row >> 1) & 3);
      af[mi] = *reinterpret_cast<const bf16x8_t*>(base + (row*4 + gs)*8);
    }
  };
  auto readB = [&](int buf){
    const unsigned short* base = lds + buf*12288 + 4096;
    #pragma unroll
    for (int ni=0;ni<4;ni++){
      int row = wn*64 + ni*16 + qi;
      int gs = g ^ ((row >> 1) & 3);
      bfr[ni] = *reinterpret_cast<const bf16x8_t*>(base + (row*4 + gs)*8);
    }
  };

  stage(0,0); stage(1,1);
  asm volatile("s_waitcnt vmcnt(3)" ::: "memory");
  __builtin_amdgcn_sched_barrier(0);
  __builtin_amdgcn_s_barrier();

  for (int it=0; it<21; ++it){
    const int t3 = it*3;
    V3_PHASE(0, t3+0);
    V3_PHASE(1, t3+1);
    V3_PHASE(2, t3+2);
  }
  V3_PHASE(0, 63);
  asm volatile("s_waitcnt vmcnt(0)" ::: "memory");  // drain clamp-dup DMA

  if (MODE == 2){
    #pragma unroll
    for (int mi=0;mi<4;mi++)
      #pragma unroll
      for (int ni=0;ni<4;ni++)
        #pragma unroll
        for (int r=0;r<4;r++){
          int mm = m0 + wm*64 + mi*16 + 4*g + r;
          int nn = n0 + wn*64 + ni*16 + qi;
          ((float*)Cout)[(size_t)mm*N + nn] = acc[mi][ni][r];
        }
    return;
  }
  // MODE 1: which is block-uniform (n0 multiple of 256, which-boundary = 2048)
  const int which = n0 >> 11;
  if (which == 2){
    // V: direct scatter to (B,H,T,D)
    #pragma unroll
    for (int mi=0;mi<4;mi++)
      #pragma unroll
      for (int ni=0;ni<4;ni++)
        #pragma unroll
        for (int r=0;r<4;r++){
          int mm = m0 + wm*64 + mi*16 + 4*g + r;
          int nn = n0 + wn*64 + ni*16 + qi;
          int bb2 = mm >> 11, t = mm & (T_SEQ-1);
          int hh = (nn >> 7) & 15, d = nn & (DHEAD-1);
          ((unsigned short*)Cout)[(size_t)2*8388608 +
              (((size_t)bb2*NHEAD + hh)*T_SEQ + t)*DHEAD + d] = f2bf(acc[mi][ni][r]);
        }
    return;
  }
  // Q or K: fused RoPE + RMSNorm.  LDS ring is fully drained (vmcnt(0)) —
  // barrier, then reuse lds[0..32768) u16 (64 KB) as X[256 rows][128 d] bf16,
  // row = head_local*128 + t_local.
  __builtin_amdgcn_s_barrier();
  {
    unsigned short* X = lds;
    #pragma unroll
    for (int mi=0;mi<4;mi++){
      #pragma unroll
      for (int ni=0;ni<4;ni++){
        int col = wn*64 + ni*16 + qi;           // 0..255
        int d = col & 127, hl = col >> 7;
        #pragma unroll
        for (int r=0;r<4;r++){
          int tl = wm*64 + mi*16 + 4*g + r;
          X[(hl*128 + tl)*128 + d] = f2bf(acc[mi][ni][r]);
        }
      }
    }
    __syncthreads();
    unsigned short* dst = (unsigned short*)Cout + (size_t)which*8388608;
    const int h0 = (n0 & 2047) >> 7;
    for (int j=0;j<32;j++){
      int rho = wv*32 + j;                      // 0..255
      int hl = rho >> 7, tl = rho & 127;
      int mm = m0 + tl;
      int b = mm >> 11, t = mm & (T_SEQ-1);
      float x1 = bf2f(X[rho*128 + lane]);
      float x2 = bf2f(X[rho*128 + lane + 64]);
      float c = cosT[t*64 + lane];
      float s = sinT[t*64 + lane];
      float o1 = x1*c + x2*s;
      float o2 = x2*c - x1*s;
      float ssum = o1*o1 + o2*o2;
      #pragma unroll
      for (int off=1; off<64; off<<=1) ssum += __shfl_xor(ssum, off, 64);
      float scale = rsqrtf(ssum*(1.f/128.f) + 1.1920929e-07f);
      unsigned short* rowp = dst + (((size_t)b*NHEAD + h0 + hl)*T_SEQ + t)*DHEAD;
      rowp[lane]      = f2bf(o1*scale);
      rowp[lane + 64] = f2bf(o2*scale);
    }
  }
}

// -------- gates (vectorized) + x cast fused.  4 rows/block, grid BT/4. --------
#define GROWS 4
__global__ __launch_bounds__(256) void gates_kernel(const float* __restrict__ x,
    const float* __restrict__ WgT, const float* __restrict__ fgb,
    float* __restrict__ lfg, unsigned short* __restrict__ xb){
  __shared__ float xs[GROWS*2048];      // 32 KB
  __shared__ float part[GROWS*32*8];    // 4 KB
  const int r0 = blockIdx.x*GROWS;
  const int tid = threadIdx.x;
  const float* xp = x + (size_t)r0*CDIM;
  #pragma unroll
  for (int i=0;i<GROWS*2048/(256*4); i++){
    int e = (i*256+tid)*4;
    *(float4*)(xs+e) = *(const float4*)(xp+e);
  }
  __syncthreads();
  #pragma unroll
  for (int i=0;i<GROWS*2048/(256*8); i++){
    int e = (i*256+tid)*8;
    u16x8_t ob;
    #pragma unroll
    for (int j=0;j<8;j++) ob[j] = f2bf(xs[e+j]);
    *reinterpret_cast<u16x8_t*>(xb + (size_t)r0*CDIM + e) = ob;
  }
  const int c = tid & 31, kseg = tid >> 5;
  const float* wp = WgT + c*2048 + kseg*256;
  const float* xq = xs + kseg*256;
  f32x4_t acc[GROWS] = {};
  for (int kk=0; kk<64; kk++){
    f32x4_t wv = *(const f32x4_t*)(wp + kk*4);
    #pragma unroll
    for (int r=0;r<GROWS;r++){
      f32x4_t xv = *(const f32x4_t*)(xq + r*2048 + kk*4);
      acc[r] += xv*wv;
    }
  }
  #pragma unroll
  for (int r=0;r<GROWS;r++)
    part[(r*32 + c)*8 + kseg] = acc[r][0]+acc[r][1]+acc[r][2]+acc[r][3];
  __syncthreads();
  if (tid < GROWS*32){
    const int r = tid >> 5, c2 = tid & 31;
    const float* pp = part + (r*32+c2)*8;
    float s = pp[0]+pp[1]+pp[2]+pp[3]+pp[4]+pp[5]+pp[6]+pp[7];
    float other = __shfl_xor(s, 16, 64);
    if (c2 < 16){
      float df = s, dl = other;
      float lam = (dl > 0.f) ? (dl + 1.f) : __expf(dl);   // elu + 1
      float logit = (df + fgb[c2]) * lam;
      float ls = fminf(logit, 0.f) - log1pf(__expf(-fabsf(logit))); // log_sigmoid
      float lf = ls / (lam + 0.001f);
      int row = r0 + r;
      int b = row >> 11, t = row & (T_SEQ-1);
      lfg[((size_t)b*NHEAD + c2)*T_SEQ + t] = lf;
    }
  }
}

// ---------------- inclusive cumsum along T per (b,h) ----------------
__global__ __launch_bounds__(256) void cumsum_kernel(const float* __restrict__ lfg,
                                                     float* __restrict__ cumF){
  __shared__ float sums[256];
  const int bh = blockIdx.x;
  const float* in = lfg + (size_t)bh*T_SEQ;
  float* out = cumF + (size_t)bh*T_SEQ;
  const int tid = threadIdx.x;
  float4 a = *(const float4*)(in + tid*8);
  float4 b = *(const float4*)(in + tid*8 + 4);
  float v[8] = {a.x,a.y,a.z,a.w,b.x,b.y,b.z,b.w};
  float run = 0.f;
  #pragma unroll
  for (int e=0;e<8;e++) run += v[e];
  sums[tid] = run;
  __syncthreads();
  for (int off=1; off<256; off<<=1){
    float y = (tid >= off) ? sums[tid-off] : 0.f;
    __syncthreads();
    sums[tid] += y;
    __syncthreads();
  }
  float acc = sums[tid] - run;  // exclusive prefix
  float o[8];
  #pragma unroll
  for (int e=0;e<8;e++){ acc += v[e]; o[e] = acc; }
  *(float4*)(out + tid*8)     = make_float4(o[0],o[1],o[2],o[3]);
  *(float4*)(out + tid*8 + 4) = make_float4(o[4],o[5],o[6],o[7]);
}

// ---------------- windowed gated attention (QBLK=128, R9-verified) ----------------
__global__ __launch_bounds__(256, 2) void attn_kernel(const unsigned short* __restrict__ Qh,
    const unsigned short* __restrict__ Kh, const unsigned short* __restrict__ Vh,
    const float* __restrict__ cumF, unsigned short* __restrict__ Y,
    const int* __restrict__ winp){
  __shared__ unsigned short smem[32768];     // 64 KB: K0|K1|V0|V1 (8192 elems each)
  const int dlin = blockIdx.y*16 + blockIdx.x;
  const int c8 = dlin & 7, klin = dlin >> 3;
  const int bh = c8 + 8*(klin >> 4);
  const int q0b = (klin & 15)*128;
  const int b = bh >> 4, h = bh & 15;
  const int tid = threadIdx.x, lane = tid & 63, wv = tid >> 6;
  const int g = lane >> 4, qi = lane & 15;
  const int win = *winp;
  const unsigned short* Qp = Qh + (size_t)bh*T_SEQ*DHEAD;
  const unsigned short* Kp = Kh + (size_t)bh*T_SEQ*DHEAD;
  const unsigned short* Vp = Vh + (size_t)bh*T_SEQ*DHEAD;
  const float* cF = cumF + (size_t)bh*T_SEQ;
  const int q0w = q0b + wv*32;
  bf16x8_t qf[2][4];
  float cFq[2];
  #pragma unroll
  for (int qb=0;qb<2;qb++){
    cFq[qb] = cF[q0w + qb*16 + qi];
    #pragma unroll
    for (int dt=0;dt<4;dt++)
      qf[qb][dt] = *reinterpret_cast<const bf16x8_t*>(Qp + (size_t)(q0w + qb*16 + qi)*DHEAD + dt*32 + g*8);
  }
  f32x4_t ot[2][8] = {};
  float mrun[2] = {-1e30f, -1e30f}, lrun[2] = {0.f, 0.f};
  const float sm_scale = 0.08838834764831845f;  // 1/sqrt(128)
  int kbeg = q0b - win + 1; if (kbeg < 0) kbeg = 0; kbeg &= ~63;
  const int nt = (q0b + 128 - kbeg) >> 6;

  auto stage = [&](int bi, int k0s){
    unsigned short* Kd = smem + bi*8192;
    unsigned short* Vd = smem + 16384 + bi*8192;
    #pragma unroll
    for (int jj=0;jj<4;jj++){
      int t = (wv*4+jj)*64 + lane;
      int r = t>>4, cc = t&15;
      __builtin_amdgcn_global_load_lds(
        (const __attribute__((address_space(1))) void*)(Kp + (size_t)(k0s+r)*DHEAD + ((cc ^ (r&7))*8)),
        (__attribute__((address_space(3))) void*)(Kd + t*8), 16, 0, 0);
      int dd = t>>7, kq = (t>>3)&15, rr = (t>>1)&3, hb = t&1;
      __builtin_amdgcn_global_load_lds(
        (const __attribute__((address_space(1))) void*)(Vp + (size_t)(k0s + kq*4 + rr)*DHEAD + dd*16 + hb*8),
        (__attribute__((address_space(3))) void*)(Vd + t*8), 16, 0, 0);
    }
  };

  stage(0, kbeg);
  for (int it=0; it<nt; ++it){
    const int k0 = kbeg + it*64;
    const int cur = it & 1;
    __syncthreads();
    if (it+1 < nt) stage(cur^1, k0+64);
    if (k0 <= q0w+31 && (k0 + 63) >= (q0w - win + 1)){
      const unsigned short* Kc = smem + cur*8192;
      f32x4_t s[2][4] = {};
      __builtin_amdgcn_s_setprio(1);
      #pragma unroll
      for (int dt=0;dt<4;dt++){
        bf16x8_t kf[4];
        #pragma unroll
        for (int kb=0;kb<4;kb++){
          int row = kb*16 + qi;
          kf[kb] = *reinterpret_cast<const bf16x8_t*>(Kc + row*128 + (((dt*4+g) ^ (row&7))*8));
        }
        #pragma unroll
        for (int kb=0;kb<4;kb++){
          s[0][kb] = __builtin_amdgcn_mfma_f32_16x16x32_bf16(kf[kb], qf[0][dt], s[0][kb], 0,0,0);
          s[1][kb] = __builtin_amdgcn_mfma_f32_16x16x32_bf16(kf[kb], qf[1][dt], s[1][kb], 0,0,0);
        }
      }
      __builtin_amdgcn_s_setprio(0);
      float4 cb[4];
      #pragma unroll
      for (int kb=0;kb<4;kb++) cb[kb] = *(const float4*)(cF + k0 + kb*16 + 4*g);
      u16x8_t pb[2][2];
      #pragma unroll
      for (int qb=0;qb<2;qb++){
        const int qg = q0w + qb*16 + qi;
        float p[16], tmax = -INFINITY;
        #pragma unroll
        for (int kb=0;kb<4;kb++){
          #pragma unroll
          for (int r=0;r<4;r++){
            int key = k0 + kb*16 + 4*g + r;
            float sv = fmaf(s[qb][kb][r], sm_scale, cFq[qb] - ((const float*)&cb[kb])[r]);
            bool ok = (key <= qg) && (qg - key < win);
            p[kb*4+r] = ok ? sv : -INFINITY;
            tmax = fmaxf(tmax, p[kb*4+r]);
          }
        }
        tmax = fmaxf(tmax, __shfl_xor(tmax, 16, 64));
        tmax = fmaxf(tmax, __shfl_xor(tmax, 32, 64));
        float mnew = fmaxf(mrun[qb], tmax);
        float alpha = __expf(mrun[qb] - mnew);
        float tsum = 0.f;
        #pragma unroll
        for (int i2=0;i2<16;i2++){ p[i2] = __expf(p[i2] - mnew); tsum += p[i2]; }
        tsum += __shfl_xor(tsum, 16, 64);
        tsum += __shfl_xor(tsum, 32, 64);
        lrun[qb] = lrun[qb]*alpha + tsum;
        mrun[qb] = mnew;
        #pragma unroll
        for (int dt=0;dt<8;dt++) ot[qb][dt] *= alpha;
        #pragma unroll
        for (int cc=0;cc<2;cc++){
          #pragma unroll
          for (int e=0;e<8;e++)
            pb[qb][cc][e] = f2bf(p[(2*cc + (e>>2))*4 + (e&3)]);
        }
      }
      unsigned vbase = ldsaddr(smem + 16384 + cur*8192) + lane*8;
      #pragma unroll
      for (int cc=0;cc<2;cc++){
        u16x4_t vlo[8], vhi[8];
        #pragma unroll
        for (int dt=0;dt<8;dt++){
          vlo[dt] = tr16(vbase + (unsigned)((dt*16 + 8*cc)*128));
          vhi[dt] = tr16(vbase + (unsigned)((dt*16 + 8*cc + 4)*128));
        }
        asm volatile("s_waitcnt lgkmcnt(0)");
        __builtin_amdgcn_sched_barrier(0);
        __builtin_amdgcn_s_setprio(1);
        #pragma unroll
        for (int dt=0;dt<8;dt++){
          u16x8_t vv = __builtin_shufflevector(vlo[dt], vhi[dt], 0,1,2,3,4,5,6,7);
          bf16x8_t vf = *reinterpret_cast<bf16x8_t*>(&vv);
          ot[0][dt] = __builtin_amdgcn_mfma_f32_16x16x32_bf16(vf, *reinterpret_cast<bf16x8_t*>(&pb[0][cc]), ot[0][dt], 0,0,0);
          ot[1][dt] = __builtin_amdgcn_mfma_f32_16x16x32_bf16(vf, *reinterpret_cast<bf16x8_t*>(&pb[1][cc]), ot[1][dt], 0,0,0);
        }
        __builtin_amdgcn_s_setprio(0);
      }
    }
  }
  __syncthreads();
  float invl[2] = {1.f/lrun[0], 1.f/lrun[1]};
  #pragma unroll
  for (int qb=0;qb<2;qb++){
    int qlocal = wv*32 + qb*16 + qi;
    #pragma unroll
    for (int dt=0;dt<8;dt++){
      int d8 = dt*2 + (g>>1);
      u16x4_t w;
      #pragma unroll
      for (int r=0;r<4;r++) w[r] = f2bf(ot[qb][dt][r]*invl[qb]);
      *reinterpret_cast<u16x4_t*>(smem + qlocal*128 + ((d8 ^ (qlocal&7))*8) + 4*(g&1)) = w;
    }
  }
  __syncthreads();
  #pragma unroll
  for (int i=0;i<8;i++){
    int t = i*256 + tid;
    int row = t>>4, cc = t&15;
    u16x8_t v = *reinterpret_cast<const u16x8_t*>(smem + row*128 + ((cc ^ (row&7))*8));
    *reinterpret_cast<u16x8_t*>(Y + ((size_t)b*T_SEQ + q0b + row)*CDIM + h*DHEAD + cc*8) = v;
  }
}

extern "C" void kernel_launch(void* const* d_in, const int* in_sizes, int n_in,
                              void* d_out, int out_size, void* d_ws, size_t ws_size,
                              hipStream_t stream){
  const float* x    = (const float*)d_in[0];
  const float* cosT = (const float*)d_in[1];
  const float* sinT = (const float*)d_in[2];
  const float* Wq   = (const float*)d_in[3];
  const float* Wk   = (const float*)d_in[4];
  const float* Wv   = (const float*)d_in[5];
  const float* Wo   = (const float*)d_in[6];
  const float* fgw  = (const float*)d_in[7];
  const float* fgb  = (const float*)d_in[8];
  const float* wlam = (const float*)d_in[9];
  const int*   winp = (const int*)d_in[10];

  char* ws = (char*)d_ws;
  unsigned short* xb    = (unsigned short*)(ws + 0);          // 16 MB
  unsigned short* WqkvT = (unsigned short*)(ws + 16777216);   // 24 MB [6144][2048] bf16 (N,K)
  unsigned short* WoT   = (unsigned short*)(ws + 41943040);   // 8 MB
  unsigned short* QKVh  = (unsigned short*)(ws + 50331648);   // 48 MB: Q|K|V each (B,H,T,D)
  unsigned short* Qh = QKVh;
  unsigned short* Kh = QKVh + 8388608;
  unsigned short* Vh = QKVh + 16777216;
  unsigned short* Yb  = (unsigned short*)(ws + 100663296);    // 16 MB
  float* lfg  = (float*)(ws + 117440512);                     // 256 KB
  float* cumF = (float*)(ws + 117702656);                     // 256 KB
  float* WgT  = (float*)(ws + 117964800);                     // 256 KB [32][2048] f32

  build_wgt<<<256, 256, 0, stream>>>(fgw, wlam, WgT);
  gates_kernel<<<BT/GROWS, 256, 0, stream>>>(x, WgT, fgb, lfg, xb);
  cumsum_kernel<<<BHT, 256, 0, stream>>>(lfg, cumF);

  transpose_all<<<dim3(64,64,4), dim3(32,8), 0, stream>>>(Wq, Wk, Wv, Wo, WqkvT, WoT);

  hipFuncSetAttribute(reinterpret_cast<const void*>(&gemm_v3<1>),
      hipFuncAttributeMaxDynamicSharedMemorySize, 73728);
  hipFuncSetAttribute(reinterpret_cast<const void*>(&gemm_v3<2>),
      hipFuncAttributeMaxDynamicSharedMemorySize, 73728);

  // QKV GEMM with fused RoPE+RMSNorm epilogue (rope_rms kernel eliminated)
  gemm_v3<1><<<(BT/128)*(NQKV/256), 512, 73728, stream>>>(xb, WqkvT, QKVh, cosT, sinT, BT, NQKV, CDIM);

  attn_kernel<<<dim3(16, BHT), 256, 0, stream>>>(Qh, Kh, Vh, cumF, Yb, winp);

  gemm_v3<2><<<(BT/128)*(CDIM/256), 512, 73728, stream>>>(Yb, WoT, d_out, nullptr, nullptr, BT, CDIM, CDIM);
}

// Round 14
// 283.670 us; speedup vs baseline: 1.1157x; 1.1157x over previous
//
#include <hip/hip_runtime.h>
#include <hip/hip_bf16.h>
#include <stdint.h>

#define T_SEQ 2048
#define CDIM  2048
#define NHEAD 16
#define DHEAD 128
#define BT    4096   // B*T
#define BHT   32     // B*H
#define NQKV  6144

typedef __bf16 bf16x8_t __attribute__((ext_vector_type(8)));
typedef float  f32x4_t  __attribute__((ext_vector_type(4)));
typedef unsigned short u16x8_t __attribute__((ext_vector_type(8)));
typedef unsigned short u16x4_t __attribute__((ext_vector_type(4)));

__device__ __forceinline__ unsigned short f2bf(float f){
  unsigned int u = __float_as_uint(f);
  u += 0x7fffu + ((u >> 16) & 1u);
  return (unsigned short)(u >> 16);
}
__device__ __forceinline__ float bf2f(unsigned short h){
  return __uint_as_float(((unsigned int)h) << 16);
}
__device__ __forceinline__ unsigned ldsaddr(const void* p){
  return (unsigned)(size_t)(const __attribute__((address_space(3))) void*)p;
}
__device__ __forceinline__ u16x4_t tr16(unsigned a){
  u16x4_t r;
  asm volatile("ds_read_b64_tr_b16 %0, %1" : "=v"(r) : "v"(a));
  return r;
}

// ------- fused transpose+cast for all 4 weight matrices (grid.z selects) -------
__global__ __launch_bounds__(256) void transpose_all(const float* __restrict__ Wq,
    const float* __restrict__ Wk, const float* __restrict__ Wv,
    const float* __restrict__ Wo, unsigned short* __restrict__ WqkvT,
    unsigned short* __restrict__ WoT){
  __shared__ float tile[32][33];
  const int z = blockIdx.z;
  const float* W = (z==0)?Wq:(z==1)?Wk:(z==2)?Wv:Wo;
  unsigned short* Wt = (z<3) ? (WqkvT + (size_t)z*4194304) : WoT;
  int n0 = blockIdx.x*32, k0 = blockIdx.y*32;
  int tx = threadIdx.x, ty = threadIdx.y;  // 32 x 8
  #pragma unroll
  for (int i=0;i<32;i+=8)
    tile[ty+i][tx] = W[(size_t)(k0+ty+i)*CDIM + n0 + tx];
  __syncthreads();
  #pragma unroll
  for (int i=0;i<32;i+=8)
    Wt[(size_t)(n0+ty+i)*CDIM + k0 + tx] = f2bf(tile[tx][ty+i]);
}

// ---------------- build WgT[32][2048]: c<16 -> fgw[:,c], c>=16 -> wlam[:,c-16] ----------------
__global__ __launch_bounds__(256) void build_wgt(const float* __restrict__ fgw,
                                                 const float* __restrict__ wlam,
                                                 float* __restrict__ WgT){
  int idx = blockIdx.x*256 + threadIdx.x;   // [0, 65536)
  int c = idx >> 11, k = idx & 2047;
  const float* W = (c < 16) ? fgw : wlam;
  WgT[idx] = W[k*16 + (c & 15)];
}

// ========== shared ring-3 phase machinery (T2+T4+T5) ==========
#define V3_SYNC() do{ __builtin_amdgcn_sched_barrier(0); \
  __builtin_amdgcn_s_barrier(); \
  asm volatile("s_waitcnt lgkmcnt(0)" ::: "memory"); \
  __builtin_amdgcn_sched_barrier(0); }while(0)

#define V3_TAIL() do{ asm volatile("s_waitcnt vmcnt(3)" ::: "memory"); \
  __builtin_amdgcn_sched_barrier(0); \
  __builtin_amdgcn_s_barrier(); }while(0)

#define V3_MFMA() do{ __builtin_amdgcn_s_setprio(1); \
  _Pragma("unroll") for (int mi=0;mi<4;mi++) \
  _Pragma("unroll") for (int ni=0;ni<4;ni++) \
    acc[mi][ni] = __builtin_amdgcn_mfma_f32_16x16x32_bf16(af[mi], bfr[ni], acc[mi][ni],0,0,0); \
  __builtin_amdgcn_s_setprio(0); }while(0)

#define V3_PHASE(BUF, TIDX) do{ \
  readA(BUF); readB(BUF); \
  { int ts_ = (TIDX)+2; if (ts_ > ntm1) ts_ = ntm1; stage(((BUF)+2)%3, ts_); } \
  V3_SYNC(); V3_MFMA(); V3_TAIL(); }while(0)

// ========== 128x256 ring-3 GEMM (R9-verified).  MODE 1: bf16 scatter to
// 3x(B,H,T,D); MODE 2: f32 plain ==========
template<int MODE>
__global__ __launch_bounds__(512, 2) void gemm_v3(const unsigned short* __restrict__ A,
                                                  const unsigned short* __restrict__ Bt,
                                                  void* __restrict__ Cout,
                                                  int M, int N, int K){
  extern __shared__ unsigned short lds[];
  const int nx = N >> 8;               // n-tiles (256 wide)
  const int Mt = M >> 7;               // m-tiles (128 tall)
  const int bid = blockIdx.x;
  const int c8 = bid & 7, w = bid >> 3;
  const int mh = Mt >> 1;
  const int mt = (c8 & 1)*mh + (w % mh);
  const int ntc = (c8 >> 1)*(nx >> 2) + (w / mh);
  const int m0 = mt << 7, n0 = ntc << 8;
  const int tid = threadIdx.x, lane = tid & 63, wv = tid >> 6;
  const int wm = wv >> 2, wn = wv & 3;
  const int g = lane >> 4, qi = lane & 15;
  const int ntm1 = (K >> 5) - 1;

  f32x4_t acc[4][4] = {};
  bf16x8_t af[4], bfr[4];

  int goffA, goffB[2];
  { int s = tid; int row = s >> 2; int lg = (s & 3) ^ ((row >> 1) & 3);
    goffA = row*K + lg*8; }
  #pragma unroll
  for (int j=0;j<2;j++){
    int s = j*512 + tid;
    int row = s >> 2;
    int lg = (s & 3) ^ ((row >> 1) & 3);
    goffB[j] = row*K + lg*8;
  }

  auto stage = [&](int buf, int kt){
    const unsigned short* srcA = A + (size_t)m0*K + kt*32;
    const unsigned short* srcB = Bt + (size_t)n0*K + kt*32;
    unsigned short* base = lds + buf*12288;
    __builtin_amdgcn_global_load_lds(
        (const __attribute__((address_space(1))) void*)(srcA + goffA),
        (__attribute__((address_space(3))) void*)(base + tid*8), 16, 0, 0);
    #pragma unroll
    for (int j=0;j<2;j++)
      __builtin_amdgcn_global_load_lds(
        (const __attribute__((address_space(1))) void*)(srcB + goffB[j]),
        (__attribute__((address_space(3))) void*)(base + 4096 + (j*512 + tid)*8), 16, 0, 0);
  };
  auto readA = [&](int buf){
    const unsigned short* base = lds + buf*12288;
    #pragma unroll
    for (int mi=0;mi<4;mi++){
      int row = wm*64 + mi*16 + qi;
      int gs = g ^ ((row >> 1) & 3);
      af[mi] = *reinterpret_cast<const bf16x8_t*>(base + (row*4 + gs)*8);
    }
  };
  auto readB = [&](int buf){
    const unsigned short* base = lds + buf*12288 + 4096;
    #pragma unroll
    for (int ni=0;ni<4;ni++){
      int row = wn*64 + ni*16 + qi;
      int gs = g ^ ((row >> 1) & 3);
      bfr[ni] = *reinterpret_cast<const bf16x8_t*>(base + (row*4 + gs)*8);
    }
  };

  stage(0,0); stage(1,1);
  asm volatile("s_waitcnt vmcnt(3)" ::: "memory");
  __builtin_amdgcn_sched_barrier(0);
  __builtin_amdgcn_s_barrier();

  for (int it=0; it<21; ++it){
    const int t3 = it*3;
    V3_PHASE(0, t3+0);
    V3_PHASE(1, t3+1);
    V3_PHASE(2, t3+2);
  }
  V3_PHASE(0, 63);
  asm volatile("s_waitcnt vmcnt(0)" ::: "memory");

  #pragma unroll
  for (int mi=0;mi<4;mi++){
    #pragma unroll
    for (int ni=0;ni<4;ni++){
      #pragma unroll
      for (int r=0;r<4;r++){
        int mm = m0 + wm*64 + mi*16 + 4*g + r;
        int nn = n0 + wn*64 + ni*16 + qi;
        float v = acc[mi][ni][r];
        if (MODE == 2){
          ((float*)Cout)[(size_t)mm*N + nn] = v;
        } else {
          int bb2 = mm >> 11, t = mm & (T_SEQ-1);
          int which = nn >> 11;             // 0=Q 1=K 2=V
          int hh = (nn >> 7) & 15, d = nn & (DHEAD-1);
          ((unsigned short*)Cout)[(size_t)which*8388608 +
              (((size_t)bb2*NHEAD + hh)*T_SEQ + t)*DHEAD + d] = f2bf(v);
        }
      }
    }
  }
}

// -------- gates (vectorized) + x cast fused.  4 rows/block, grid BT/4. --------
#define GROWS 4
__global__ __launch_bounds__(256) void gates_kernel(const float* __restrict__ x,
    const float* __restrict__ WgT, const float* __restrict__ fgb,
    float* __restrict__ lfg, unsigned short* __restrict__ xb){
  __shared__ float xs[GROWS*2048];      // 32 KB
  __shared__ float part[GROWS*32*8];    // 4 KB
  const int r0 = blockIdx.x*GROWS;
  const int tid = threadIdx.x;
  const float* xp = x + (size_t)r0*CDIM;
  #pragma unroll
  for (int i=0;i<GROWS*2048/(256*4); i++){
    int e = (i*256+tid)*4;
    *(float4*)(xs+e) = *(const float4*)(xp+e);
  }
  __syncthreads();
  #pragma unroll
  for (int i=0;i<GROWS*2048/(256*8); i++){
    int e = (i*256+tid)*8;
    u16x8_t ob;
    #pragma unroll
    for (int j=0;j<8;j++) ob[j] = f2bf(xs[e+j]);
    *reinterpret_cast<u16x8_t*>(xb + (size_t)r0*CDIM + e) = ob;
  }
  const int c = tid & 31, kseg = tid >> 5;
  const float* wp = WgT + c*2048 + kseg*256;
  const float* xq = xs + kseg*256;
  f32x4_t acc[GROWS] = {};
  for (int kk=0; kk<64; kk++){
    f32x4_t wv = *(const f32x4_t*)(wp + kk*4);
    #pragma unroll
    for (int r=0;r<GROWS;r++){
      f32x4_t xv = *(const f32x4_t*)(xq + r*2048 + kk*4);
      acc[r] += xv*wv;
    }
  }
  #pragma unroll
  for (int r=0;r<GROWS;r++)
    part[(r*32 + c)*8 + kseg] = acc[r][0]+acc[r][1]+acc[r][2]+acc[r][3];
  __syncthreads();
  if (tid < GROWS*32){
    const int r = tid >> 5, c2 = tid & 31;
    const float* pp = part + (r*32+c2)*8;
    float s = pp[0]+pp[1]+pp[2]+pp[3]+pp[4]+pp[5]+pp[6]+pp[7];
    float other = __shfl_xor(s, 16, 64);
    if (c2 < 16){
      float df = s, dl = other;
      float lam = (dl > 0.f) ? (dl + 1.f) : __expf(dl);   // elu + 1
      float logit = (df + fgb[c2]) * lam;
      float ls = fminf(logit, 0.f) - log1pf(__expf(-fabsf(logit))); // log_sigmoid
      float lf = ls / (lam + 0.001f);
      int row = r0 + r;
      int b = row >> 11, t = row & (T_SEQ-1);
      lfg[((size_t)b*NHEAD + c2)*T_SEQ + t] = lf;
    }
  }
}

// ---------------- inclusive cumsum along T per (b,h) ----------------
__global__ __launch_bounds__(256) void cumsum_kernel(const float* __restrict__ lfg,
                                                     float* __restrict__ cumF){
  __shared__ float sums[256];
  const int bh = blockIdx.x;
  const float* in = lfg + (size_t)bh*T_SEQ;
  float* out = cumF + (size_t)bh*T_SEQ;
  const int tid = threadIdx.x;
  float4 a = *(const float4*)(in + tid*8);
  float4 b = *(const float4*)(in + tid*8 + 4);
  float v[8] = {a.x,a.y,a.z,a.w,b.x,b.y,b.z,b.w};
  float run = 0.f;
  #pragma unroll
  for (int e=0;e<8;e++) run += v[e];
  sums[tid] = run;
  __syncthreads();
  for (int off=1; off<256; off<<=1){
    float y = (tid >= off) ? sums[tid-off] : 0.f;
    __syncthreads();
    sums[tid] += y;
    __syncthreads();
  }
  float acc = sums[tid] - run;  // exclusive prefix
  float o[8];
  #pragma unroll
  for (int e=0;e<8;e++){ acc += v[e]; o[e] = acc; }
  *(float4*)(out + tid*8)     = make_float4(o[0],o[1],o[2],o[3]);
  *(float4*)(out + tid*8 + 4) = make_float4(o[4],o[5],o[6],o[7]);
}

// ---------------- in-place RoPE + RMSNorm on Q and K (fused) ----------------
__global__ __launch_bounds__(256) void rope_rms(unsigned short* __restrict__ QK,
    const float* __restrict__ cosT, const float* __restrict__ sinT){
  const int tid = threadIdx.x, lane = tid & 63, wv = tid >> 6;
  const int idx2 = blockIdx.x*4 + wv;       // [0, 2*BHT*T_SEQ)
  const int which = idx2 >> 16;             // 0=Q, 1=K  (BHT*T_SEQ = 65536)
  const int row = idx2 & 65535;             // (b*H + h)*T + t
  const int t = row & (T_SEQ-1);
  unsigned short* xp = QK + (size_t)which*8388608 + (size_t)row*DHEAD;
  float x1 = bf2f(xp[lane]);
  float x2 = bf2f(xp[lane+64]);
  float c = cosT[t*64 + lane];
  float s = sinT[t*64 + lane];
  float o1 = x1*c + x2*s;
  float o2 = x2*c - x1*s;
  float ss = o1*o1 + o2*o2;
  #pragma unroll
  for (int off=1; off<64; off<<=1) ss += __shfl_xor(ss, off, 64);
  float scale = rsqrtf(ss*(1.f/128.f) + 1.1920929e-07f);
  xp[lane]    = f2bf(o1*scale);
  xp[lane+64] = f2bf(o2*scale);
}

// ---------------- windowed gated attention (QBLK=128, R9-verified) ----------------
__global__ __launch_bounds__(256, 2) void attn_kernel(const unsigned short* __restrict__ Qh,
    const unsigned short* __restrict__ Kh, const unsigned short* __restrict__ Vh,
    const float* __restrict__ cumF, unsigned short* __restrict__ Y,
    const int* __restrict__ winp){
  __shared__ unsigned short smem[32768];     // 64 KB: K0|K1|V0|V1 (8192 elems each)
  const int dlin = blockIdx.y*16 + blockIdx.x;
  const int c8 = dlin & 7, klin = dlin >> 3;
  const int bh = c8 + 8*(klin >> 4);
  const int q0b = (klin & 15)*128;
  const int b = bh >> 4, h = bh & 15;
  const int tid = threadIdx.x, lane = tid & 63, wv = tid >> 6;
  const int g = lane >> 4, qi = lane & 15;
  const int win = *winp;
  const unsigned short* Qp = Qh + (size_t)bh*T_SEQ*DHEAD;
  const unsigned short* Kp = Kh + (size_t)bh*T_SEQ*DHEAD;
  const unsigned short* Vp = Vh + (size_t)bh*T_SEQ*DHEAD;
  const float* cF = cumF + (size_t)bh*T_SEQ;
  const int q0w = q0b + wv*32;
  bf16x8_t qf[2][4];
  float cFq[2];
  #pragma unroll
  for (int qb=0;qb<2;qb++){
    cFq[qb] = cF[q0w + qb*16 + qi];
    #pragma unroll
    for (int dt=0;dt<4;dt++)
      qf[qb][dt] = *reinterpret_cast<const bf16x8_t*>(Qp + (size_t)(q0w + qb*16 + qi)*DHEAD + dt*32 + g*8);
  }
  f32x4_t ot[2][8] = {};
  float mrun[2] = {-1e30f, -1e30f}, lrun[2] = {0.f, 0.f};
  const float sm_scale = 0.08838834764831845f;  // 1/sqrt(128)
  int kbeg = q0b - win + 1; if (kbeg < 0) kbeg = 0; kbeg &= ~63;
  const int nt = (q0b + 128 - kbeg) >> 6;

  auto stage = [&](int bi, int k0s){
    unsigned short* Kd = smem + bi*8192;
    unsigned short* Vd = smem + 16384 + bi*8192;
    #pragma unroll
    for (int jj=0;jj<4;jj++){
      int t = (wv*4+jj)*64 + lane;
      int r = t>>4, cc = t&15;
      __builtin_amdgcn_global_load_lds(
        (const __attribute__((address_space(1))) void*)(Kp + (size_t)(k0s+r)*DHEAD + ((cc ^ (r&7))*8)),
        (__attribute__((address_space(3))) void*)(Kd + t*8), 16, 0, 0);
      int dd = t>>7, kq = (t>>3)&15, rr = (t>>1)&3, hb = t&1;
      __builtin_amdgcn_global_load_lds(
        (const __attribute__((address_space(1))) void*)(Vp + (size_t)(k0s + kq*4 + rr)*DHEAD + dd*16 + hb*8),
        (__attribute__((address_space(3))) void*)(Vd + t*8), 16, 0, 0);
    }
  };

  stage(0, kbeg);
  for (int it=0; it<nt; ++it){
    const int k0 = kbeg + it*64;
    const int cur = it & 1;
    __syncthreads();
    if (it+1 < nt) stage(cur^1, k0+64);
    if (k0 <= q0w+31 && (k0 + 63) >= (q0w - win + 1)){
      const unsigned short* Kc = smem + cur*8192;
      f32x4_t s[2][4] = {};
      __builtin_amdgcn_s_setprio(1);
      #pragma unroll
      for (int dt=0;dt<4;dt++){
        bf16x8_t kf[4];
        #pragma unroll
        for (int kb=0;kb<4;kb++){
          int row = kb*16 + qi;
          kf[kb] = *reinterpret_cast<const bf16x8_t*>(Kc + row*128 + (((dt*4+g) ^ (row&7))*8));
        }
        #pragma unroll
        for (int kb=0;kb<4;kb++){
          s[0][kb] = __builtin_amdgcn_mfma_f32_16x16x32_bf16(kf[kb], qf[0][dt], s[0][kb], 0,0,0);
          s[1][kb] = __builtin_amdgcn_mfma_f32_16x16x32_bf16(kf[kb], qf[1][dt], s[1][kb], 0,0,0);
        }
      }
      __builtin_amdgcn_s_setprio(0);
      float4 cb[4];
      #pragma unroll
      for (int kb=0;kb<4;kb++) cb[kb] = *(const float4*)(cF + k0 + kb*16 + 4*g);
      u16x8_t pb[2][2];
      #pragma unroll
      for (int qb=0;qb<2;qb++){
        const int qg = q0w + qb*16 + qi;
        float p[16], tmax = -INFINITY;
        #pragma unroll
        for (int kb=0;kb<4;kb++){
          #pragma unroll
          for (int r=0;r<4;r++){
            int key = k0 + kb*16 + 4*g + r;
            float sv = fmaf(s[qb][kb][r], sm_scale, cFq[qb] - ((const float*)&cb[kb])[r]);
            bool ok = (key <= qg) && (qg - key < win);
            p[kb*4+r] = ok ? sv : -INFINITY;
            tmax = fmaxf(tmax, p[kb*4+r]);
          }
        }
        tmax = fmaxf(tmax, __shfl_xor(tmax, 16, 64));
        tmax = fmaxf(tmax, __shfl_xor(tmax, 32, 64));
        float mnew = fmaxf(mrun[qb], tmax);
        float alpha = __expf(mrun[qb] - mnew);
        float tsum = 0.f;
        #pragma unroll
        for (int i2=0;i2<16;i2++){ p[i2] = __expf(p[i2] - mnew); tsum += p[i2]; }
        tsum += __shfl_xor(tsum, 16, 64);
        tsum += __shfl_xor(tsum, 32, 64);
        lrun[qb] = lrun[qb]*alpha + tsum;
        mrun[qb] = mnew;
        #pragma unroll
        for (int dt=0;dt<8;dt++) ot[qb][dt] *= alpha;
        #pragma unroll
        for (int cc=0;cc<2;cc++){
          #pragma unroll
          for (int e=0;e<8;e++)
            pb[qb][cc][e] = f2bf(p[(2*cc + (e>>2))*4 + (e&3)]);
        }
      }
      unsigned vbase = ldsaddr(smem + 16384 + cur*8192) + lane*8;
      #pragma unroll
      for (int cc=0;cc<2;cc++){
        u16x4_t vlo[8], vhi[8];
        #pragma unroll
        for (int dt=0;dt<8;dt++){
          vlo[dt] = tr16(vbase + (unsigned)((dt*16 + 8*cc)*128));
          vhi[dt] = tr16(vbase + (unsigned)((dt*16 + 8*cc + 4)*128));
        }
        asm volatile("s_waitcnt lgkmcnt(0)");
        __builtin_amdgcn_sched_barrier(0);
        __builtin_amdgcn_s_setprio(1);
        #pragma unroll
        for (int dt=0;dt<8;dt++){
          u16x8_t vv = __builtin_shufflevector(vlo[dt], vhi[dt], 0,1,2,3,4,5,6,7);
          bf16x8_t vf = *reinterpret_cast<bf16x8_t*>(&vv);
          ot[0][dt] = __builtin_amdgcn_mfma_f32_16x16x32_bf16(vf, *reinterpret_cast<bf16x8_t*>(&pb[0][cc]), ot[0][dt], 0,0,0);
          ot[1][dt] = __builtin_amdgcn_mfma_f32_16x16x32_bf16(vf, *reinterpret_cast<bf16x8_t*>(&pb[1][cc]), ot[1][dt], 0,0,0);
        }
        __builtin_amdgcn_s_setprio(0);
      }
    }
  }
  __syncthreads();
  float invl[2] = {1.f/lrun[0], 1.f/lrun[1]};
  #pragma unroll
  for (int qb=0;qb<2;qb++){
    int qlocal = wv*32 + qb*16 + qi;
    #pragma unroll
    for (int dt=0;dt<8;dt++){
      int d8 = dt*2 + (g>>1);
      u16x4_t w;
      #pragma unroll
      for (int r=0;r<4;r++) w[r] = f2bf(ot[qb][dt][r]*invl[qb]);
      *reinterpret_cast<u16x4_t*>(smem + qlocal*128 + ((d8 ^ (qlocal&7))*8) + 4*(g&1)) = w;
    }
  }
  __syncthreads();
  #pragma unroll
  for (int i=0;i<8;i++){
    int t = i*256 + tid;
    int row = t>>4, cc = t&15;
    u16x8_t v = *reinterpret_cast<const u16x8_t*>(smem + row*128 + ((cc ^ (row&7))*8));
    *reinterpret_cast<u16x8_t*>(Y + ((size_t)b*T_SEQ + q0b + row)*CDIM + h*DHEAD + cc*8) = v;
  }
}

extern "C" void kernel_launch(void* const* d_in, const int* in_sizes, int n_in,
                              void* d_out, int out_size, void* d_ws, size_t ws_size,
                              hipStream_t stream){
  const float* x    = (const float*)d_in[0];
  const float* cosT = (const float*)d_in[1];
  const float* sinT = (const float*)d_in[2];
  const float* Wq   = (const float*)d_in[3];
  const float* Wk   = (const float*)d_in[4];
  const float* Wv   = (const float*)d_in[5];
  const float* Wo   = (const float*)d_in[6];
  const float* fgw  = (const float*)d_in[7];
  const float* fgb  = (const float*)d_in[8];
  const float* wlam = (const float*)d_in[9];
  const int*   winp = (const int*)d_in[10];

  char* ws = (char*)d_ws;
  unsigned short* xb    = (unsigned short*)(ws + 0);          // 16 MB
  unsigned short* WqkvT = (unsigned short*)(ws + 16777216);   // 24 MB [6144][2048] bf16 (N,K)
  unsigned short* WoT   = (unsigned short*)(ws + 41943040);   // 8 MB
  unsigned short* QKVh  = (unsigned short*)(ws + 50331648);   // 48 MB: Q|K|V each (B,H,T,D)
  unsigned short* Qh = QKVh;
  unsigned short* Kh = QKVh + 8388608;
  unsigned short* Vh = QKVh + 16777216;
  unsigned short* Yb  = (unsigned short*)(ws + 100663296);    // 16 MB
  float* lfg  = (float*)(ws + 117440512);                     // 256 KB
  float* cumF = (float*)(ws + 117702656);                     // 256 KB
  float* WgT  = (float*)(ws + 117964800);                     // 256 KB [32][2048] f32

  build_wgt<<<256, 256, 0, stream>>>(fgw, wlam, WgT);
  gates_kernel<<<BT/GROWS, 256, 0, stream>>>(x, WgT, fgb, lfg, xb);
  cumsum_kernel<<<BHT, 256, 0, stream>>>(lfg, cumF);

  transpose_all<<<dim3(64,64,4), dim3(32,8), 0, stream>>>(Wq, Wk, Wv, Wo, WqkvT, WoT);

  hipFuncSetAttribute(reinterpret_cast<const void*>(&gemm_v3<1>),
      hipFuncAttributeMaxDynamicSharedMemorySize, 73728);
  hipFuncSetAttribute(reinterpret_cast<const void*>(&gemm_v3<2>),
      hipFuncAttributeMaxDynamicSharedMemorySize, 73728);

  gemm_v3<1><<<(BT/128)*(NQKV/256), 512, 73728, stream>>>(xb, WqkvT, QKVh, BT, NQKV, CDIM);

  rope_rms<<<2*BHT*T_SEQ/4, 256, 0, stream>>>(QKVh, cosT, sinT);  // Q and K fused

  attn_kernel<<<dim3(16, BHT), 256, 0, stream>>>(Qh, Kh, Vh, cumF, Yb, winp);

  gemm_v3<2><<<(BT/128)*(CDIM/256), 512, 73728, stream>>>(Yb, WoT, d_out, BT, CDIM, CDIM);
}

// Round 15
// 280.521 us; speedup vs baseline: 1.1282x; 1.0112x over previous
//
#include <hip/hip_runtime.h>
#include <hip/hip_bf16.h>
#include <stdint.h>

#define T_SEQ 2048
#define CDIM  2048
#define NHEAD 16
#define DHEAD 128
#define BT    4096   // B*T
#define BHT   32     // B*H
#define NQKV  6144

typedef __bf16 bf16x8_t __attribute__((ext_vector_type(8)));
typedef float  f32x4_t  __attribute__((ext_vector_type(4)));
typedef unsigned short u16x8_t __attribute__((ext_vector_type(8)));
typedef unsigned short u16x4_t __attribute__((ext_vector_type(4)));

__device__ __forceinline__ unsigned short f2bf(float f){
  unsigned int u = __float_as_uint(f);
  u += 0x7fffu + ((u >> 16) & 1u);
  return (unsigned short)(u >> 16);
}
__device__ __forceinline__ float bf2f(unsigned short h){
  return __uint_as_float(((unsigned int)h) << 16);
}
__device__ __forceinline__ unsigned ldsaddr(const void* p){
  return (unsigned)(size_t)(const __attribute__((address_space(3))) void*)p;
}
__device__ __forceinline__ u16x4_t tr16(unsigned a){
  u16x4_t r;
  asm volatile("ds_read_b64_tr_b16 %0, %1" : "=v"(r) : "v"(a));
  return r;
}

// ------- fused transpose+cast for all 4 weight matrices (grid.z selects) -------
__global__ __launch_bounds__(256) void transpose_all(const float* __restrict__ Wq,
    const float* __restrict__ Wk, const float* __restrict__ Wv,
    const float* __restrict__ Wo, unsigned short* __restrict__ WqkvT,
    unsigned short* __restrict__ WoT){
  __shared__ float tile[32][33];
  const int z = blockIdx.z;
  const float* W = (z==0)?Wq:(z==1)?Wk:(z==2)?Wv:Wo;
  unsigned short* Wt = (z<3) ? (WqkvT + (size_t)z*4194304) : WoT;
  int n0 = blockIdx.x*32, k0 = blockIdx.y*32;
  int tx = threadIdx.x, ty = threadIdx.y;  // 32 x 8
  #pragma unroll
  for (int i=0;i<32;i+=8)
    tile[ty+i][tx] = W[(size_t)(k0+ty+i)*CDIM + n0 + tx];
  __syncthreads();
  #pragma unroll
  for (int i=0;i<32;i+=8)
    Wt[(size_t)(n0+ty+i)*CDIM + k0 + tx] = f2bf(tile[tx][ty+i]);
}

// ---------------- build WgT[32][2048]: c<16 -> fgw[:,c], c>=16 -> wlam[:,c-16] ----------------
__global__ __launch_bounds__(256) void build_wgt(const float* __restrict__ fgw,
                                                 const float* __restrict__ wlam,
                                                 float* __restrict__ WgT){
  int idx = blockIdx.x*256 + threadIdx.x;   // [0, 65536)
  int c = idx >> 11, k = idx & 2047;
  const float* W = (c < 16) ? fgw : wlam;
  WgT[idx] = W[k*16 + (c & 15)];
}

// ========== shared ring-3 phase machinery (T2+T4+T5) ==========
#define V3_SYNC() do{ __builtin_amdgcn_sched_barrier(0); \
  __builtin_amdgcn_s_barrier(); \
  asm volatile("s_waitcnt lgkmcnt(0)" ::: "memory"); \
  __builtin_amdgcn_sched_barrier(0); }while(0)

#define V3_TAIL() do{ asm volatile("s_waitcnt vmcnt(3)" ::: "memory"); \
  __builtin_amdgcn_sched_barrier(0); \
  __builtin_amdgcn_s_barrier(); }while(0)

#define V3_MFMA() do{ __builtin_amdgcn_s_setprio(1); \
  _Pragma("unroll") for (int mi=0;mi<4;mi++) \
  _Pragma("unroll") for (int ni=0;ni<4;ni++) \
    acc[mi][ni] = __builtin_amdgcn_mfma_f32_16x16x32_bf16(af[mi], bfr[ni], acc[mi][ni],0,0,0); \
  __builtin_amdgcn_s_setprio(0); }while(0)

#define V3_PHASE(BUF, TIDX) do{ \
  readA(BUF); readB(BUF); \
  { int ts_ = (TIDX)+2; if (ts_ > ntm1) ts_ = ntm1; stage(((BUF)+2)%3, ts_); } \
  V3_SYNC(); V3_MFMA(); V3_TAIL(); }while(0)

// ========== 128x256 ring-3 GEMM (R9-verified).  MODE 1: bf16 scatter to
// 3x(B,H,T,D); MODE 2: f32 plain ==========
template<int MODE>
__global__ __launch_bounds__(512, 2) void gemm_v3(const unsigned short* __restrict__ A,
                                                  const unsigned short* __restrict__ Bt,
                                                  void* __restrict__ Cout,
                                                  int M, int N, int K){
  extern __shared__ unsigned short lds[];
  const int nx = N >> 8;               // n-tiles (256 wide)
  const int Mt = M >> 7;               // m-tiles (128 tall)
  const int bid = blockIdx.x;
  const int c8 = bid & 7, w = bid >> 3;
  const int mh = Mt >> 1;
  const int mt = (c8 & 1)*mh + (w % mh);
  const int ntc = (c8 >> 1)*(nx >> 2) + (w / mh);
  const int m0 = mt << 7, n0 = ntc << 8;
  const int tid = threadIdx.x, lane = tid & 63, wv = tid >> 6;
  const int wm = wv >> 2, wn = wv & 3;
  const int g = lane >> 4, qi = lane & 15;
  const int ntm1 = (K >> 5) - 1;

  f32x4_t acc[4][4] = {};
  bf16x8_t af[4], bfr[4];

  int goffA, goffB[2];
  { int s = tid; int row = s >> 2; int lg = (s & 3) ^ ((row >> 1) & 3);
    goffA = row*K + lg*8; }
  #pragma unroll
  for (int j=0;j<2;j++){
    int s = j*512 + tid;
    int row = s >> 2;
    int lg = (s & 3) ^ ((row >> 1) & 3);
    goffB[j] = row*K + lg*8;
  }

  auto stage = [&](int buf, int kt){
    const unsigned short* srcA = A + (size_t)m0*K + kt*32;
    const unsigned short* srcB = Bt + (size_t)n0*K + kt*32;
    unsigned short* base = lds + buf*12288;
    __builtin_amdgcn_global_load_lds(
        (const __attribute__((address_space(1))) void*)(srcA + goffA),
        (__attribute__((address_space(3))) void*)(base + tid*8), 16, 0, 0);
    #pragma unroll
    for (int j=0;j<2;j++)
      __builtin_amdgcn_global_load_lds(
        (const __attribute__((address_space(1))) void*)(srcB + goffB[j]),
        (__attribute__((address_space(3))) void*)(base + 4096 + (j*512 + tid)*8), 16, 0, 0);
  };
  auto readA = [&](int buf){
    const unsigned short* base = lds + buf*12288;
    #pragma unroll
    for (int mi=0;mi<4;mi++){
      int row = wm*64 + mi*16 + qi;
      int gs = g ^ ((row >> 1) & 3);
      af[mi] = *reinterpret_cast<const bf16x8_t*>(base + (row*4 + gs)*8);
    }
  };
  auto readB = [&](int buf){
    const unsigned short* base = lds + buf*12288 + 4096;
    #pragma unroll
    for (int ni=0;ni<4;ni++){
      int row = wn*64 + ni*16 + qi;
      int gs = g ^ ((row >> 1) & 3);
      bfr[ni] = *reinterpret_cast<const bf16x8_t*>(base + (row*4 + gs)*8);
    }
  };

  stage(0,0); stage(1,1);
  asm volatile("s_waitcnt vmcnt(3)" ::: "memory");
  __builtin_amdgcn_sched_barrier(0);
  __builtin_amdgcn_s_barrier();

  for (int it=0; it<21; ++it){
    const int t3 = it*3;
    V3_PHASE(0, t3+0);
    V3_PHASE(1, t3+1);
    V3_PHASE(2, t3+2);
  }
  V3_PHASE(0, 63);
  asm volatile("s_waitcnt vmcnt(0)" ::: "memory");

  #pragma unroll
  for (int mi=0;mi<4;mi++){
    #pragma unroll
    for (int ni=0;ni<4;ni++){
      #pragma unroll
      for (int r=0;r<4;r++){
        int mm = m0 + wm*64 + mi*16 + 4*g + r;
        int nn = n0 + wn*64 + ni*16 + qi;
        float v = acc[mi][ni][r];
        if (MODE == 2){
          ((float*)Cout)[(size_t)mm*N + nn] = v;
        } else {
          int bb2 = mm >> 11, t = mm & (T_SEQ-1);
          int which = nn >> 11;             // 0=Q 1=K 2=V
          int hh = (nn >> 7) & 15, d = nn & (DHEAD-1);
          ((unsigned short*)Cout)[(size_t)which*8388608 +
              (((size_t)bb2*NHEAD + hh)*T_SEQ + t)*DHEAD + d] = f2bf(v);
        }
      }
    }
  }
}

// -------- gates (vectorized) + x cast fused.  4 rows/block, grid BT/4. --------
#define GROWS 4
__global__ __launch_bounds__(256) void gates_kernel(const float* __restrict__ x,
    const float* __restrict__ WgT, const float* __restrict__ fgb,
    float* __restrict__ lfg, unsigned short* __restrict__ xb){
  __shared__ float xs[GROWS*2048];      // 32 KB
  __shared__ float part[GROWS*32*8];    // 4 KB
  const int r0 = blockIdx.x*GROWS;
  const int tid = threadIdx.x;
  const float* xp = x + (size_t)r0*CDIM;
  #pragma unroll
  for (int i=0;i<GROWS*2048/(256*4); i++){
    int e = (i*256+tid)*4;
    *(float4*)(xs+e) = *(const float4*)(xp+e);
  }
  __syncthreads();
  #pragma unroll
  for (int i=0;i<GROWS*2048/(256*8); i++){
    int e = (i*256+tid)*8;
    u16x8_t ob;
    #pragma unroll
    for (int j=0;j<8;j++) ob[j] = f2bf(xs[e+j]);
    *reinterpret_cast<u16x8_t*>(xb + (size_t)r0*CDIM + e) = ob;
  }
  const int c = tid & 31, kseg = tid >> 5;
  const float* wp = WgT + c*2048 + kseg*256;
  const float* xq = xs + kseg*256;
  f32x4_t acc[GROWS] = {};
  for (int kk=0; kk<64; kk++){
    f32x4_t wv = *(const f32x4_t*)(wp + kk*4);
    #pragma unroll
    for (int r=0;r<GROWS;r++){
      f32x4_t xv = *(const f32x4_t*)(xq + r*2048 + kk*4);
      acc[r] += xv*wv;
    }
  }
  #pragma unroll
  for (int r=0;r<GROWS;r++)
    part[(r*32 + c)*8 + kseg] = acc[r][0]+acc[r][1]+acc[r][2]+acc[r][3];
  __syncthreads();
  if (tid < GROWS*32){
    const int r = tid >> 5, c2 = tid & 31;
    const float* pp = part + (r*32+c2)*8;
    float s = pp[0]+pp[1]+pp[2]+pp[3]+pp[4]+pp[5]+pp[6]+pp[7];
    float other = __shfl_xor(s, 16, 64);
    if (c2 < 16){
      float df = s, dl = other;
      float lam = (dl > 0.f) ? (dl + 1.f) : __expf(dl);   // elu + 1
      float logit = (df + fgb[c2]) * lam;
      float ls = fminf(logit, 0.f) - log1pf(__expf(-fabsf(logit))); // log_sigmoid
      float lf = ls / (lam + 0.001f);
      int row = r0 + r;
      int b = row >> 11, t = row & (T_SEQ-1);
      lfg[((size_t)b*NHEAD + c2)*T_SEQ + t] = lf;
    }
  }
}

// ---------------- inclusive cumsum along T per (b,h) ----------------
__global__ __launch_bounds__(256) void cumsum_kernel(const float* __restrict__ lfg,
                                                     float* __restrict__ cumF){
  __shared__ float sums[256];
  const int bh = blockIdx.x;
  const float* in = lfg + (size_t)bh*T_SEQ;
  float* out = cumF + (size_t)bh*T_SEQ;
  const int tid = threadIdx.x;
  float4 a = *(const float4*)(in + tid*8);
  float4 b = *(const float4*)(in + tid*8 + 4);
  float v[8] = {a.x,a.y,a.z,a.w,b.x,b.y,b.z,b.w};
  float run = 0.f;
  #pragma unroll
  for (int e=0;e<8;e++) run += v[e];
  sums[tid] = run;
  __syncthreads();
  for (int off=1; off<256; off<<=1){
    float y = (tid >= off) ? sums[tid-off] : 0.f;
    __syncthreads();
    sums[tid] += y;
    __syncthreads();
  }
  float acc = sums[tid] - run;  // exclusive prefix
  float o[8];
  #pragma unroll
  for (int e=0;e<8;e++){ acc += v[e]; o[e] = acc; }
  *(float4*)(out + tid*8)     = make_float4(o[0],o[1],o[2],o[3]);
  *(float4*)(out + tid*8 + 4) = make_float4(o[4],o[5],o[6],o[7]);
}

// ---------------- in-place RoPE + RMSNorm on K only (Q fused into attn) ----------------
__global__ __launch_bounds__(256) void rope_rms(unsigned short* __restrict__ Kh,
    const float* __restrict__ cosT, const float* __restrict__ sinT){
  const int tid = threadIdx.x, lane = tid & 63, wv = tid >> 6;
  const int row = blockIdx.x*4 + wv;        // (b*H + h)*T + t, [0, 65536)
  const int t = row & (T_SEQ-1);
  unsigned short* xp = Kh + (size_t)row*DHEAD;
  float x1 = bf2f(xp[lane]);
  float x2 = bf2f(xp[lane+64]);
  float c = cosT[t*64 + lane];
  float s = sinT[t*64 + lane];
  float o1 = x1*c + x2*s;
  float o2 = x2*c - x1*s;
  float ss = o1*o1 + o2*o2;
  #pragma unroll
  for (int off=1; off<64; off<<=1) ss += __shfl_xor(ss, off, 64);
  float scale = rsqrtf(ss*(1.f/128.f) + 1.1920929e-07f);
  xp[lane]    = f2bf(o1*scale);
  xp[lane+64] = f2bf(o2*scale);
}

// ---------------- windowed gated attention (QBLK=128) + fused Q RoPE/RMSNorm ----------------
__global__ __launch_bounds__(256, 2) void attn_kernel(const unsigned short* __restrict__ Qh,
    const unsigned short* __restrict__ Kh, const unsigned short* __restrict__ Vh,
    const float* __restrict__ cumF, unsigned short* __restrict__ Y,
    const int* __restrict__ winp, const float* __restrict__ cosT,
    const float* __restrict__ sinT){
  __shared__ unsigned short smem[32768];     // 64 KB: K0|K1|V0|V1 (8192 elems each)
  const int dlin = blockIdx.y*16 + blockIdx.x;
  const int c8 = dlin & 7, klin = dlin >> 3;
  const int bh = c8 + 8*(klin >> 4);
  const int q0b = (klin & 15)*128;
  const int b = bh >> 4, h = bh & 15;
  const int tid = threadIdx.x, lane = tid & 63, wv = tid >> 6;
  const int g = lane >> 4, qi = lane & 15;
  const int win = *winp;
  const unsigned short* Qp = Qh + (size_t)bh*T_SEQ*DHEAD;
  const unsigned short* Kp = Kh + (size_t)bh*T_SEQ*DHEAD;
  const unsigned short* Vp = Vh + (size_t)bh*T_SEQ*DHEAD;
  const float* cF = cumF + (size_t)bh*T_SEQ;
  const int q0w = q0b + wv*32;
  bf16x8_t qf[2][4];
  float cFq[2];
  #pragma unroll
  for (int qb=0;qb<2;qb++){
    const int qg = q0w + qb*16 + qi;
    const int t = qg & (T_SEQ-1);
    cFq[qb] = cF[qg];
    #pragma unroll
    for (int dt=0;dt<4;dt++)
      qf[qb][dt] = *reinterpret_cast<const bf16x8_t*>(Qp + (size_t)qg*DHEAD + dt*32 + g*8);
    // fused RoPE + RMSNorm on this Q row (raw bf16 from the QKV GEMM):
    // lane holds d = dt*32 + g*8 + e; pair (d, d+64) = (dt, dt+2), same lane.
    // row spread across 4 lanes (g = lane>>4) -> shfl_xor(16/32) reduce.
    float o[4][8];
    float ssum = 0.f;
    #pragma unroll
    for (int dt=0;dt<2;dt++){
      const float* cp = cosT + t*64 + dt*32 + g*8;
      const float* sp = sinT + t*64 + dt*32 + g*8;
      float4 ca = *(const float4*)cp, cb4 = *(const float4*)(cp+4);
      float4 sa = *(const float4*)sp, sb4 = *(const float4*)(sp+4);
      float cc[8] = {ca.x,ca.y,ca.z,ca.w,cb4.x,cb4.y,cb4.z,cb4.w};
      float sv[8] = {sa.x,sa.y,sa.z,sa.w,sb4.x,sb4.y,sb4.z,sb4.w};
      #pragma unroll
      for (int e=0;e<8;e++){
        float x1 = bf2f(((const u16x8_t*)&qf[qb][dt])[0][e]);
        float x2 = bf2f(((const u16x8_t*)&qf[qb][dt+2])[0][e]);
        float o1 = fmaf(x1, cc[e],  x2*sv[e]);
        float o2 = fmaf(x2, cc[e], -x1*sv[e]);
        o[dt][e] = o1; o[dt+2][e] = o2;
        ssum = fmaf(o1, o1, fmaf(o2, o2, ssum));
      }
    }
    ssum += __shfl_xor(ssum, 16, 64);
    ssum += __shfl_xor(ssum, 32, 64);
    float scale = rsqrtf(ssum*(1.f/128.f) + 1.1920929e-07f);
    #pragma unroll
    for (int dt=0;dt<4;dt++){
      u16x8_t w;
      #pragma unroll
      for (int e=0;e<8;e++) w[e] = f2bf(o[dt][e]*scale);
      qf[qb][dt] = *reinterpret_cast<bf16x8_t*>(&w);
    }
  }
  f32x4_t ot[2][8] = {};
  float mrun[2] = {-1e30f, -1e30f}, lrun[2] = {0.f, 0.f};
  const float sm_scale = 0.08838834764831845f;  // 1/sqrt(128)
  int kbeg = q0b - win + 1; if (kbeg < 0) kbeg = 0; kbeg &= ~63;
  const int nt = (q0b + 128 - kbeg) >> 6;

  auto stage = [&](int bi, int k0s){
    unsigned short* Kd = smem + bi*8192;
    unsigned short* Vd = smem + 16384 + bi*8192;
    #pragma unroll
    for (int jj=0;jj<4;jj++){
      int t = (wv*4+jj)*64 + lane;
      int r = t>>4, cc = t&15;
      __builtin_amdgcn_global_load_lds(
        (const __attribute__((address_space(1))) void*)(Kp + (size_t)(k0s+r)*DHEAD + ((cc ^ (r&7))*8)),
        (__attribute__((address_space(3))) void*)(Kd + t*8), 16, 0, 0);
      int dd = t>>7, kq = (t>>3)&15, rr = (t>>1)&3, hb = t&1;
      __builtin_amdgcn_global_load_lds(
        (const __attribute__((address_space(1))) void*)(Vp + (size_t)(k0s + kq*4 + rr)*DHEAD + dd*16 + hb*8),
        (__attribute__((address_space(3))) void*)(Vd + t*8), 16, 0, 0);
    }
  };

  stage(0, kbeg);
  for (int it=0; it<nt; ++it){
    const int k0 = kbeg + it*64;
    const int cur = it & 1;
    __syncthreads();
    if (it+1 < nt) stage(cur^1, k0+64);
    if (k0 <= q0w+31 && (k0 + 63) >= (q0w - win + 1)){
      const unsigned short* Kc = smem + cur*8192;
      f32x4_t s[2][4] = {};
      __builtin_amdgcn_s_setprio(1);
      #pragma unroll
      for (int dt=0;dt<4;dt++){
        bf16x8_t kf[4];
        #pragma unroll
        for (int kb=0;kb<4;kb++){
          int row = kb*16 + qi;
          kf[kb] = *reinterpret_cast<const bf16x8_t*>(Kc + row*128 + (((dt*4+g) ^ (row&7))*8));
        }
        #pragma unroll
        for (int kb=0;kb<4;kb++){
          s[0][kb] = __builtin_amdgcn_mfma_f32_16x16x32_bf16(kf[kb], qf[0][dt], s[0][kb], 0,0,0);
          s[1][kb] = __builtin_amdgcn_mfma_f32_16x16x32_bf16(kf[kb], qf[1][dt], s[1][kb], 0,0,0);
        }
      }
      __builtin_amdgcn_s_setprio(0);
      float4 cb[4];
      #pragma unroll
      for (int kb=0;kb<4;kb++) cb[kb] = *(const float4*)(cF + k0 + kb*16 + 4*g);
      u16x8_t pb[2][2];
      #pragma unroll
      for (int qb=0;qb<2;qb++){
        const int qg = q0w + qb*16 + qi;
        float p[16], tmax = -INFINITY;
        #pragma unroll
        for (int kb=0;kb<4;kb++){
          #pragma unroll
          for (int r=0;r<4;r++){
            int key = k0 + kb*16 + 4*g + r;
            float sv = fmaf(s[qb][kb][r], sm_scale, cFq[qb] - ((const float*)&cb[kb])[r]);
            bool ok = (key <= qg) && (qg - key < win);
            p[kb*4+r] = ok ? sv : -INFINITY;
            tmax = fmaxf(tmax, p[kb*4+r]);
          }
        }
        tmax = fmaxf(tmax, __shfl_xor(tmax, 16, 64));
        tmax = fmaxf(tmax, __shfl_xor(tmax, 32, 64));
        float mnew = fmaxf(mrun[qb], tmax);
        float alpha = __expf(mrun[qb] - mnew);
        float tsum = 0.f;
        #pragma unroll
        for (int i2=0;i2<16;i2++){ p[i2] = __expf(p[i2] - mnew); tsum += p[i2]; }
        tsum += __shfl_xor(tsum, 16, 64);
        tsum += __shfl_xor(tsum, 32, 64);
        lrun[qb] = lrun[qb]*alpha + tsum;
        mrun[qb] = mnew;
        #pragma unroll
        for (int dt=0;dt<8;dt++) ot[qb][dt] *= alpha;
        #pragma unroll
        for (int cc=0;cc<2;cc++){
          #pragma unroll
          for (int e=0;e<8;e++)
            pb[qb][cc][e] = f2bf(p[(2*cc + (e>>2))*4 + (e&3)]);
        }
      }
      unsigned vbase = ldsaddr(smem + 16384 + cur*8192) + lane*8;
      #pragma unroll
      for (int cc=0;cc<2;cc++){
        u16x4_t vlo[8], vhi[8];
        #pragma unroll
        for (int dt=0;dt<8;dt++){
          vlo[dt] = tr16(vbase + (unsigned)((dt*16 + 8*cc)*128));
          vhi[dt] = tr16(vbase + (unsigned)((dt*16 + 8*cc + 4)*128));
        }
        asm volatile("s_waitcnt lgkmcnt(0)");
        __builtin_amdgcn_sched_barrier(0);
        __builtin_amdgcn_s_setprio(1);
        #pragma unroll
        for (int dt=0;dt<8;dt++){
          u16x8_t vv = __builtin_shufflevector(vlo[dt], vhi[dt], 0,1,2,3,4,5,6,7);
          bf16x8_t vf = *reinterpret_cast<bf16x8_t*>(&vv);
          ot[0][dt] = __builtin_amdgcn_mfma_f32_16x16x32_bf16(vf, *reinterpret_cast<bf16x8_t*>(&pb[0][cc]), ot[0][dt], 0,0,0);
          ot[1][dt] = __builtin_amdgcn_mfma_f32_16x16x32_bf16(vf, *reinterpret_cast<bf16x8_t*>(&pb[1][cc]), ot[1][dt], 0,0,0);
        }
        __builtin_amdgcn_s_setprio(0);
      }
    }
  }
  __syncthreads();
  float invl[2] = {1.f/lrun[0], 1.f/lrun[1]};
  #pragma unroll
  for (int qb=0;qb<2;qb++){
    int qlocal = wv*32 + qb*16 + qi;
    #pragma unroll
    for (int dt=0;dt<8;dt++){
      int d8 = dt*2 + (g>>1);
      u16x4_t w;
      #pragma unroll
      for (int r=0;r<4;r++) w[r] = f2bf(ot[qb][dt][r]*invl[qb]);
      *reinterpret_cast<u16x4_t*>(smem + qlocal*128 + ((d8 ^ (qlocal&7))*8) + 4*(g&1)) = w;
    }
  }
  __syncthreads();
  #pragma unroll
  for (int i=0;i<8;i++){
    int t = i*256 + tid;
    int row = t>>4, cc = t&15;
    u16x8_t v = *reinterpret_cast<const u16x8_t*>(smem + row*128 + ((cc ^ (row&7))*8));
    *reinterpret_cast<u16x8_t*>(Y + ((size_t)b*T_SEQ + q0b + row)*CDIM + h*DHEAD + cc*8) = v;
  }
}

extern "C" void kernel_launch(void* const* d_in, const int* in_sizes, int n_in,
                              void* d_out, int out_size, void* d_ws, size_t ws_size,
                              hipStream_t stream){
  const float* x    = (const float*)d_in[0];
  const float* cosT = (const float*)d_in[1];
  const float* sinT = (const float*)d_in[2];
  const float* Wq   = (const float*)d_in[3];
  const float* Wk   = (const float*)d_in[4];
  const float* Wv   = (const float*)d_in[5];
  const float* Wo   = (const float*)d_in[6];
  const float* fgw  = (const float*)d_in[7];
  const float* fgb  = (const float*)d_in[8];
  const float* wlam = (const float*)d_in[9];
  const int*   winp = (const int*)d_in[10];

  char* ws = (char*)d_ws;
  unsigned short* xb    = (unsigned short*)(ws + 0);          // 16 MB
  unsigned short* WqkvT = (unsigned short*)(ws + 16777216);   // 24 MB [6144][2048] bf16 (N,K)
  unsigned short* WoT   = (unsigned short*)(ws + 41943040);   // 8 MB
  unsigned short* QKVh  = (unsigned short*)(ws + 50331648);   // 48 MB: Q|K|V each (B,H,T,D)
  unsigned short* Qh = QKVh;
  unsigned short* Kh = QKVh + 8388608;
  unsigned short* Vh = QKVh + 16777216;
  unsigned short* Yb  = (unsigned short*)(ws + 100663296);    // 16 MB
  float* lfg  = (float*)(ws + 117440512);                     // 256 KB
  float* cumF = (float*)(ws + 117702656);                     // 256 KB
  float* WgT  = (float*)(ws + 117964800);                     // 256 KB [32][2048] f32

  build_wgt<<<256, 256, 0, stream>>>(fgw, wlam, WgT);
  gates_kernel<<<BT/GROWS, 256, 0, stream>>>(x, WgT, fgb, lfg, xb);
  cumsum_kernel<<<BHT, 256, 0, stream>>>(lfg, cumF);

  transpose_all<<<dim3(64,64,4), dim3(32,8), 0, stream>>>(Wq, Wk, Wv, Wo, WqkvT, WoT);

  hipFuncSetAttribute(reinterpret_cast<const void*>(&gemm_v3<1>),
      hipFuncAttributeMaxDynamicSharedMemorySize, 73728);
  hipFuncSetAttribute(reinterpret_cast<const void*>(&gemm_v3<2>),
      hipFuncAttributeMaxDynamicSharedMemorySize, 73728);

  gemm_v3<1><<<(BT/128)*(NQKV/256), 512, 73728, stream>>>(xb, WqkvT, QKVh, BT, NQKV, CDIM);

  rope_rms<<<BHT*T_SEQ/4, 256, 0, stream>>>(Kh, cosT, sinT);  // K only (Q fused in attn)

  attn_kernel<<<dim3(16, BHT), 256, 0, stream>>>(Qh, Kh, Vh, cumF, Yb, winp, cosT, sinT);

  gemm_v3<2><<<(BT/128)*(CDIM/256), 512, 73728, stream>>>(Yb, WoT, d_out, BT, CDIM, CDIM);
}